// Round 1
// 371.993 us; speedup vs baseline: 1.0074x; 1.0074x over previous
//
#include <hip/hip_runtime.h>
#include <hip/hip_bf16.h>

typedef __hip_bfloat16 bf16;
typedef __attribute__((ext_vector_type(8))) short short8;   // 8 bf16 (4 VGPRs)
typedef __attribute__((ext_vector_type(4))) float f32x4;

constexpr int D     = 1024;
constexpr int T     = 2048;
constexpr int BATCH = 2;
constexpr int ROWS  = BATCH * T;   // 4096
constexpr int NH    = 16;
constexpr int DKEY  = 64;
constexpr int QKVN  = 3 * D;       // 3072
constexpr int FFNN  = 4 * D;       // 4096

static __device__ __forceinline__ float b2f(bf16 x) { return __bfloat162float(x); }
static __device__ __forceinline__ bf16  f2b(float x) { return __float2bfloat16(x); }
static __device__ __forceinline__ float loadf(const bf16* p)  { return __bfloat162float(*p); }
static __device__ __forceinline__ float loadf(const float* p) { return *p; }
static __device__ __forceinline__ float fast_exp2(float x) { return __builtin_amdgcn_exp2f(x); }
static __device__ __forceinline__ unsigned short f2bu(float x) {
    return __bfloat16_as_ushort(__float2bfloat16(x));
}

// ---------- fp32 [R][C] -> bf16 [C][R] transpose + downcast ----------
__global__ __launch_bounds__(256) void transpose_cast(const float* __restrict__ in,
                                                      bf16* __restrict__ out,
                                                      int R, int C)
{
    __shared__ float tile[32][33];
    int c0 = blockIdx.x * 32, r0 = blockIdx.y * 32;
    int tx = threadIdx.x & 31, ty = threadIdx.x >> 5;  // 8 rows per pass
#pragma unroll
    for (int i = 0; i < 32; i += 8)
        tile[ty + i][tx] = in[(size_t)(r0 + ty + i) * C + c0 + tx];
    __syncthreads();
#pragma unroll
    for (int i = 0; i < 32; i += 8)
        out[(size_t)(c0 + ty + i) * R + r0 + tx] = f2b(tile[tx][ty + i]);
}

// ---------- LayerNorm: one block per row of 1024, fp32 gamma/beta, bf16 out ----------
template <typename TIN>
__global__ __launch_bounds__(256) void ln_kernel(const TIN* __restrict__ X,
                                                 const float* __restrict__ g,
                                                 const float* __restrict__ b,
                                                 bf16* __restrict__ out)
{
    int row = blockIdx.x;
    int tid = threadIdx.x;
    const TIN* xr = X + (size_t)row * D;
    float v[4];
#pragma unroll
    for (int i = 0; i < 4; ++i) v[i] = loadf(xr + tid + i * 256);

    float s1 = v[0] + v[1] + v[2] + v[3];
    float s2 = v[0]*v[0] + v[1]*v[1] + v[2]*v[2] + v[3]*v[3];
#pragma unroll
    for (int off = 32; off; off >>= 1) {
        s1 += __shfl_xor(s1, off);
        s2 += __shfl_xor(s2, off);
    }
    __shared__ float red[8];
    int lane = tid & 63, w = tid >> 6;
    if (lane == 0) { red[w] = s1; red[4 + w] = s2; }
    __syncthreads();
    s1 = red[0] + red[1] + red[2] + red[3];
    s2 = red[4] + red[5] + red[6] + red[7];

    float mu   = s1 * (1.0f / D);
    float var  = s2 * (1.0f / D) - mu * mu;
    float rstd = rsqrtf(var + 1e-5f);

    bf16* orow = out + (size_t)row * D;
#pragma unroll
    for (int i = 0; i < 4; ++i) {
        int c = tid + i * 256;
        orow[c] = f2b((v[i] - mu) * rstd * g[c] + b[c]);
    }
}

// ---------- Pipelined MFMA GEMM ----------
// New this round:
//  * XCD-aware bijective block swizzle (all grids are %8==0): consecutive
//    logical n-blocks (sharing an A row-panel) land on the same XCD L2.
//  * SPLITZ: gridDim.z=2 split-K in ONE dispatch. z=0 computes K[0..K),
//    writes acc+bias+resid(bf16) as f32 to out; z=1 computes K[K..2K),
//    writes raw f32 partial to `part`. Reduced by add_partial afterwards.
//  * Kstride (row stride of A and Bt) decoupled from K (loop extent).
template <int BM, int RELU, int RES, int OUTF32, int SPLITZ = 0>
__global__ __launch_bounds__(256) void mfma_gemm(
    const bf16* __restrict__ A, const bf16* __restrict__ Bt,
    const float* __restrict__ bias, const void* __restrict__ resid,
    void* __restrict__ out, float* __restrict__ part,
    int M, int N, int K, int Kstride)
{
    constexpr int LDSK = 40;       // 32 + 8 pad (80 B stride)
    constexpr int MT   = BM / 32;  // m-frags per wave (2 or 4)
    __shared__ __align__(16) unsigned short As[2][BM * LDSK];
    __shared__ __align__(16) unsigned short Bs[2][128 * LDSK];

    // ---- XCD-aware swizzle of the flattened block id (bijective; nwg%8==0) ----
    int gx = gridDim.x, gy = gridDim.y;
    int lid = (blockIdx.z * gy + blockIdx.y) * gx + blockIdx.x;
    int nwg = gx * gy * gridDim.z;
    int chunk = nwg >> 3;
    int swz = (lid & 7) * chunk + (lid >> 3);
    int bx = swz % gx;
    int by = (swz / gx) % gy;
    int bz = swz / (gx * gy);

    int tid  = threadIdx.x;
    int m0   = by * BM, n0 = bx * 128;
    int lane = tid & 63, wave = tid >> 6;
    int wm = (wave >> 1) * (MT * 16), wn = (wave & 1) * 64;
    int c15 = lane & 15, quad = lane >> 4;

    int koff = 0;
    if constexpr (SPLITZ) koff = bz * K;

    f32x4 acc[MT][4] = {};

    int brow = tid >> 1, bseg = (tid & 1) * 16;
    int arow, aseg;
    if constexpr (BM == 128) { arow = tid >> 1; aseg = (tid & 1) * 16; }
    else                     { arow = tid >> 2; aseg = (tid & 3) * 8;  }
    const bf16* aptr = A  + (size_t)(m0 + arow) * Kstride + koff + aseg;
    const bf16* bptr = Bt + (size_t)(n0 + brow) * Kstride + koff + bseg;

    int nk = K >> 5;
    uint4 ra0, ra1, rb0, rb1;
    ra0 = *(const uint4*)(aptr);
    if constexpr (BM == 128) ra1 = *(const uint4*)(aptr + 8);
    rb0 = *(const uint4*)(bptr);
    rb1 = *(const uint4*)(bptr + 8);

    for (int kt = 0; kt < nk; ++kt) {
        int buf = kt & 1;
        {
            unsigned short* asl = &As[buf][arow * LDSK + aseg];
            unsigned short* bsl = &Bs[buf][brow * LDSK + bseg];
            *(uint4*)asl = ra0;
            if constexpr (BM == 128) *(uint4*)(asl + 8) = ra1;
            *(uint4*)bsl       = rb0;
            *(uint4*)(bsl + 8) = rb1;
        }
        __syncthreads();
        if (kt + 1 < nk) {
            int ko = (kt + 1) * 32;
            ra0 = *(const uint4*)(aptr + ko);
            if constexpr (BM == 128) ra1 = *(const uint4*)(aptr + ko + 8);
            rb0 = *(const uint4*)(bptr + ko);
            rb1 = *(const uint4*)(bptr + ko + 8);
        }
        short8 af[MT], bfr[4];
#pragma unroll
        for (int t = 0; t < MT; ++t)
            af[t]  = *(const short8*)&As[buf][(wm + t * 16 + c15) * LDSK + quad * 8];
#pragma unroll
        for (int t = 0; t < 4; ++t)
            bfr[t] = *(const short8*)&Bs[buf][(wn + t * 16 + c15) * LDSK + quad * 8];
#pragma unroll
        for (int mt = 0; mt < MT; ++mt)
#pragma unroll
            for (int nt = 0; nt < 4; ++nt)
                acc[mt][nt] = __builtin_amdgcn_mfma_f32_16x16x32_bf16(
                    af[mt], bfr[nt], acc[mt][nt], 0, 0, 0);
    }

#pragma unroll
    for (int mt = 0; mt < MT; ++mt) {
#pragma unroll
        for (int nt = 0; nt < 4; ++nt) {
            f32x4 v4 = acc[mt][nt];
            int gc = n0 + wn + nt * 16 + c15;
            float bb = (!SPLITZ || bz == 0) ? bias[gc] : 0.0f;
#pragma unroll
            for (int r = 0; r < 4; ++r) {
                int gr = m0 + wm + mt * 16 + quad * 4 + r;
                float v = v4[r] + bb;
                if constexpr (RELU) v = fmaxf(v, 0.0f);
                size_t idx = (size_t)gr * N + gc;
                if constexpr (SPLITZ) {
                    if (bz == 0) {
                        v += b2f(((const bf16*)resid)[idx]);
                        ((float*)out)[idx] = v;
                    } else {
                        part[idx] = v;
                    }
                } else {
                    if constexpr (RES == 1) v += b2f(((const bf16*)resid)[idx]);
                    if constexpr (RES == 2) v += ((const float*)resid)[idx];
                    if constexpr (OUTF32) ((float*)out)[idx] = v;
                    else                  ((bf16*)out)[idx] = f2b(v);
                }
            }
        }
    }
}

// ---------- split-K reduction: out += part (f32, vectorized) ----------
__global__ __launch_bounds__(256) void add_partial(float* __restrict__ out,
                                                   const float* __restrict__ part)
{
    int i = blockIdx.x * 256 + threadIdx.x;
    f32x4 a = ((const f32x4*)out)[i];
    f32x4 p = ((const f32x4*)part)[i];
    a += p;
    ((f32x4*)out)[i] = a;
}

// ---------- MFMA flash attention, transposed orientation + fixed-shift softmax ----------
__global__ __launch_bounds__(256) void flash_attn(const bf16* __restrict__ qkv,
                                                  bf16* __restrict__ ctx)
{
    constexpr int KROW = 72;
    constexpr float CSC = 0.18033688011112042f;  // 0.125 * log2(e)
    constexpr float MSH = 12.0f;                 // fixed exp2-domain shift

    __shared__ __align__(16) unsigned short Qs[128 * KROW];  // aliased by Pt after qf cache
    __shared__ __align__(16) unsigned short Ks[64 * KROW];   // [key][dk]
    __shared__ __align__(16) unsigned short Vt[64 * KROW];   // [dk][key]
    unsigned short* Pt = Qs;                                 // [qrow][key], wave-private rows

    int bx = blockIdx.x;
    int bh = bx & 31;
    int qi = 15 - (bx >> 5);      // heavy q-tiles first
    int h  = bh & 15, b = bh >> 4;
    int q0 = qi * 128;

    int tid = threadIdx.x, lane = tid & 63, w = tid >> 6;
    int c15 = lane & 15, quad = lane >> 4;

    const bf16* base = qkv + (size_t)b * T * QKVN;

    // --- stage Q tile [128][64] ---
    {
        int row = tid >> 1, half = tid & 1;
        const bf16* src = base + (size_t)(q0 + row) * QKVN + h * 64 + half * 32;
        unsigned short* dst = &Qs[row * KROW + half * 32];
        uint4 v0 = *(const uint4*)(src);
        uint4 v1 = *(const uint4*)(src + 8);
        uint4 v2 = *(const uint4*)(src + 16);
        uint4 v3 = *(const uint4*)(src + 24);
        *(uint4*)(dst)      = v0;
        *(uint4*)(dst + 8)  = v1;
        *(uint4*)(dst + 16) = v2;
        *(uint4*)(dst + 24) = v3;
    }
    __syncthreads();

    // Q B-fragments cached in registers (wave-private rows [w*32, w*32+32))
    short8 qf[2][2];
#pragma unroll
    for (int qt = 0; qt < 2; ++qt)
#pragma unroll
        for (int s = 0; s < 2; ++s)
            qf[qt][s] = *(const short8*)&Qs[(w * 32 + qt * 16 + c15) * KROW + s * 32 + quad * 8];

    short8 ones;
#pragma unroll
    for (int i = 0; i < 8; ++i) ones[i] = (short)0x3F80;  // bf16 1.0

    f32x4 Ot[4][2] = {};   // [dt][qt] : O^T[dk][qrow]
    f32x4 lacc[2]  = {};   // row sums per qt

    int nkt   = q0 / 64 + 2;
    int wqmin = q0 + w * 32;
    int wqmax = wqmin + 31;

    for (int kt = 0; kt < nkt; ++kt) {
        int k0 = kt * 64;
        // ---- global loads (K tile + V tile) ----
        int key = tid >> 2, seg = tid & 3;
        const bf16* ksrc = base + (size_t)(k0 + key) * QKVN + D + h * 64 + seg * 16;
        uint4 kv0 = *(const uint4*)ksrc;
        uint4 kv1 = *(const uint4*)(ksrc + 8);
        int keyp = (tid & 31) * 2, dk0 = (tid >> 5) * 8;
        const bf16* vsrc = base + (size_t)(k0 + keyp) * QKVN + 2 * D + h * 64 + dk0;
        uint4 vv0 = *(const uint4*)vsrc;
        uint4 vv1 = *(const uint4*)(vsrc + QKVN);

        __syncthreads();   // previous iteration's Ks/Vt fragment reads complete
        {
            unsigned short* kd = &Ks[key * KROW + seg * 16];
            *(uint4*)kd       = kv0;
            *(uint4*)(kd + 8) = kv1;
            const unsigned short* lo = (const unsigned short*)&vv0;
            const unsigned short* hi = (const unsigned short*)&vv1;
#pragma unroll
            for (int j = 0; j < 8; ++j) {
                unsigned int pk = (unsigned int)lo[j] | ((unsigned int)hi[j] << 16);
                *(unsigned int*)&Vt[(dk0 + j) * KROW + keyp] = pk;  // Vt[dk][key]
            }
        }
        __syncthreads();

        if (k0 <= wqmax) {   // wave-uniform: skip tiles fully above the diagonal
            // ---- S^T = K Q^T : St[ktm][qt], lane holds key=ktm*16+quad*4+r, qrow=qt*16+c15
            f32x4 St[4][2] = {};
#pragma unroll
            for (int s = 0; s < 2; ++s)
#pragma unroll
                for (int ktm = 0; ktm < 4; ++ktm) {
                    short8 kf = *(const short8*)&Ks[(ktm * 16 + c15) * KROW + s * 32 + quad * 8];
#pragma unroll
                    for (int qt = 0; qt < 2; ++qt)
                        St[ktm][qt] = __builtin_amdgcn_mfma_f32_16x16x32_bf16(
                            kf, qf[qt][s], St[ktm][qt], 0, 0, 0);
                }

            // ---- P = exp2(S*CSC - MSH) (+ causal mask on diagonal tiles), store to Pt ----
            bool diag = (k0 + 63 > wqmin);
#pragma unroll
            for (int ktm = 0; ktm < 4; ++ktm)
#pragma unroll
                for (int qt = 0; qt < 2; ++qt) {
                    ushort4 pk;
                    int q_g = wqmin + qt * 16 + c15;
#pragma unroll
                    for (int r = 0; r < 4; ++r) {
                        float p = fast_exp2(fmaf(St[ktm][qt][r], CSC, -MSH));
                        if (diag && (k0 + ktm * 16 + quad * 4 + r > q_g)) p = 0.0f;
                        ((unsigned short*)&pk)[r] = f2bu(p);
                    }
                    *(ushort4*)&Pt[(w * 32 + qt * 16 + c15) * KROW + ktm * 16 + quad * 4] = pk;
                }

            // ---- O^T += V^T P^T ; l += ones . P^T  (wave-private, no barrier) ----
#pragma unroll
            for (int s = 0; s < 2; ++s) {
                short8 pf[2];
#pragma unroll
                for (int qt = 0; qt < 2; ++qt)
                    pf[qt] = *(const short8*)&Pt[(w * 32 + qt * 16 + c15) * KROW + s * 32 + quad * 8];
#pragma unroll
                for (int qt = 0; qt < 2; ++qt)
                    lacc[qt] = __builtin_amdgcn_mfma_f32_16x16x32_bf16(ones, pf[qt], lacc[qt], 0, 0, 0);
#pragma unroll
                for (int dt = 0; dt < 4; ++dt) {
                    short8 vf = *(const short8*)&Vt[(dt * 16 + c15) * KROW + s * 32 + quad * 8];
#pragma unroll
                    for (int qt = 0; qt < 2; ++qt)
                        Ot[dt][qt] = __builtin_amdgcn_mfma_f32_16x16x32_bf16(
                            vf, pf[qt], Ot[dt][qt], 0, 0, 0);
                }
            }
        }
    }

    // ---- epilogue: ctx[qrow][h*64+dk] = O^T / l, packed 8 B stores ----
#pragma unroll
    for (int qt = 0; qt < 2; ++qt) {
        float inv = 1.0f / lacc[qt][0];
        int grow = b * T + q0 + w * 32 + qt * 16 + c15;
        bf16* dst = ctx + (size_t)grow * D + h * 64 + quad * 4;
#pragma unroll
        for (int dt = 0; dt < 4; ++dt) {
            ushort4 pk;
#pragma unroll
            for (int r = 0; r < 4; ++r)
                ((unsigned short*)&pk)[r] = f2bu(Ot[dt][qt][r] * inv);
            *(ushort4*)(dst + dt * 16) = pk;
        }
    }
}

extern "C" void kernel_launch(void* const* d_in, const int* in_sizes, int n_in,
                              void* d_out, int out_size, void* d_ws, size_t ws_size,
                              hipStream_t stream)
{
    const float* X    = (const float*)d_in[0];
    const float* Wqkv = (const float*)d_in[1];
    const float* bqkv = (const float*)d_in[2];
    const float* Wo   = (const float*)d_in[3];
    const float* bo   = (const float*)d_in[4];
    const float* W1   = (const float*)d_in[5];
    const float* b1   = (const float*)d_in[6];
    const float* W2   = (const float*)d_in[7];
    const float* b2   = (const float*)d_in[8];
    const float* ln1g = (const float*)d_in[9];
    const float* ln1b = (const float*)d_in[10];
    const float* ln2g = (const float*)d_in[11];
    const float* ln2b = (const float*)d_in[12];
    float* out = (float*)d_out;

    // Workspace (peak 72 MiB):
    char* ws = (char*)d_ws;
    bf16* Wqkv_t = (bf16*)(ws + 0);          // [3072][1024]  6 MiB
    bf16* Wo_t   = (bf16*)(ws + 6291456);    // [1024][1024]  2 MiB
    bf16* W1_t   = (bf16*)(ws + 8388608);    // [4096][1024]  8 MiB
    bf16* W2_t   = (bf16*)(ws + 16777216);   // [1024][4096]  8 MiB
    bf16* Xn     = (bf16*)(ws + 25165824);   // 8 MiB; reused by X1 after step 2
    bf16* X1     = Xn;
    bf16* qkv    = (bf16*)(ws + 33554432);   // 24 MiB; first 8 MiB reused by Xn2 after attn
    bf16* Xn2    = (bf16*)(ws + 33554432);
    bf16* ctx    = (bf16*)(ws + 58720256);   // 8 MiB
    bf16* mid    = (bf16*)(ws + 41943040);   // 32 MiB; ends at 72 MiB
    // Split-K partial for W2: reuses ws[0..16 MiB) (Wqkv_t/Wo_t/W1_t are dead
    // by the time the W2 GEMM runs).
    float* W2part = (float*)(ws + 0);        // [4096][1024] f32, exactly 16 MiB

    transpose_cast<<<dim3(QKVN / 32, D / 32), 256, 0, stream>>>(Wqkv, Wqkv_t, D, QKVN);
    transpose_cast<<<dim3(D / 32, D / 32), 256, 0, stream>>>(Wo, Wo_t, D, D);
    transpose_cast<<<dim3(FFNN / 32, D / 32), 256, 0, stream>>>(W1, W1_t, D, FFNN);
    transpose_cast<<<dim3(D / 32, FFNN / 32), 256, 0, stream>>>(W2, W2_t, FFNN, D);

    ln_kernel<float><<<ROWS, 256, 0, stream>>>(X, ln1g, ln1b, Xn);
    mfma_gemm<128, 0, 0, 0><<<dim3(QKVN / 128, ROWS / 128), 256, 0, stream>>>(
        Xn, Wqkv_t, bqkv, nullptr, qkv, nullptr, ROWS, QKVN, D, D);
    flash_attn<<<512, 256, 0, stream>>>(qkv, ctx);
    mfma_gemm<64, 0, 2, 0><<<dim3(D / 128, ROWS / 64), 256, 0, stream>>>(
        ctx, Wo_t, bo, X, X1, nullptr, ROWS, D, D, D);
    ln_kernel<bf16><<<ROWS, 256, 0, stream>>>(X1, ln2g, ln2b, Xn2);
    mfma_gemm<128, 1, 0, 0><<<dim3(FFNN / 128, ROWS / 128), 256, 0, stream>>>(
        Xn2, W1_t, b1, nullptr, mid, nullptr, ROWS, FFNN, D, D);
    // W2: split-K=2 in one dispatch (z=0: K[0,2048) -> out with bias+resid;
    // z=1: K[2048,4096) -> raw f32 partial), then out += partial.
    mfma_gemm<64, 0, 1, 1, 1><<<dim3(D / 128, ROWS / 64, 2), 256, 0, stream>>>(
        mid, W2_t, b2, X1, out, W2part, ROWS, D, FFNN / 2, FFNN);
    add_partial<<<ROWS * D / 4 / 256, 256, 0, stream>>>(out, W2part);
}

// Round 2
// 362.705 us; speedup vs baseline: 1.0332x; 1.0256x over previous
//
#include <hip/hip_runtime.h>
#include <hip/hip_bf16.h>

typedef __hip_bfloat16 bf16;
typedef __attribute__((ext_vector_type(8))) short short8;   // 8 bf16 (4 VGPRs)
typedef __attribute__((ext_vector_type(4))) float f32x4;

constexpr int D     = 1024;
constexpr int T     = 2048;
constexpr int BATCH = 2;
constexpr int ROWS  = BATCH * T;   // 4096
constexpr int NH    = 16;
constexpr int DKEY  = 64;
constexpr int QKVN  = 3 * D;       // 3072
constexpr int FFNN  = 4 * D;       // 4096

static __device__ __forceinline__ float b2f(bf16 x) { return __bfloat162float(x); }
static __device__ __forceinline__ bf16  f2b(float x) { return __float2bfloat16(x); }
static __device__ __forceinline__ float loadf(const bf16* p)  { return __bfloat162float(*p); }
static __device__ __forceinline__ float loadf(const float* p) { return *p; }
static __device__ __forceinline__ float fast_exp2(float x) { return __builtin_amdgcn_exp2f(x); }
static __device__ __forceinline__ unsigned short f2bu(float x) {
    return __bfloat16_as_ushort(__float2bfloat16(x));
}

// async global->LDS, 16 B per lane. LDS dest is wave-uniform base + lane*16.
static __device__ __forceinline__ void gload_lds16(const bf16* g, unsigned short* l) {
    __builtin_amdgcn_global_load_lds(
        (const __attribute__((address_space(1))) void*)g,
        (__attribute__((address_space(3))) void*)l,
        16, 0, 0);
}

// ---------- fp32 [R][C] -> bf16 [C][R] transpose + downcast ----------
__global__ __launch_bounds__(256) void transpose_cast(const float* __restrict__ in,
                                                      bf16* __restrict__ out,
                                                      int R, int C)
{
    __shared__ float tile[32][33];
    int c0 = blockIdx.x * 32, r0 = blockIdx.y * 32;
    int tx = threadIdx.x & 31, ty = threadIdx.x >> 5;  // 8 rows per pass
#pragma unroll
    for (int i = 0; i < 32; i += 8)
        tile[ty + i][tx] = in[(size_t)(r0 + ty + i) * C + c0 + tx];
    __syncthreads();
#pragma unroll
    for (int i = 0; i < 32; i += 8)
        out[(size_t)(c0 + ty + i) * R + r0 + tx] = f2b(tile[tx][ty + i]);
}

// ---------- LayerNorm: one block per row of 1024, fp32 gamma/beta, bf16 out ----------
template <typename TIN>
__global__ __launch_bounds__(256) void ln_kernel(const TIN* __restrict__ X,
                                                 const float* __restrict__ g,
                                                 const float* __restrict__ b,
                                                 bf16* __restrict__ out)
{
    int row = blockIdx.x;
    int tid = threadIdx.x;
    const TIN* xr = X + (size_t)row * D;
    float v[4];
#pragma unroll
    for (int i = 0; i < 4; ++i) v[i] = loadf(xr + tid + i * 256);

    float s1 = v[0] + v[1] + v[2] + v[3];
    float s2 = v[0]*v[0] + v[1]*v[1] + v[2]*v[2] + v[3]*v[3];
#pragma unroll
    for (int off = 32; off; off >>= 1) {
        s1 += __shfl_xor(s1, off);
        s2 += __shfl_xor(s2, off);
    }
    __shared__ float red[8];
    int lane = tid & 63, w = tid >> 6;
    if (lane == 0) { red[w] = s1; red[4 + w] = s2; }
    __syncthreads();
    s1 = red[0] + red[1] + red[2] + red[3];
    s2 = red[4] + red[5] + red[6] + red[7];

    float mu   = s1 * (1.0f / D);
    float var  = s2 * (1.0f / D) - mu * mu;
    float rstd = rsqrtf(var + 1e-5f);

    bf16* orow = out + (size_t)row * D;
#pragma unroll
    for (int i = 0; i < 4; ++i) {
        int c = tid + i * 256;
        orow[c] = f2b((v[i] - mu) * rstd * g[c] + b[c]);
    }
}

// ---------- MFMA GEMM, m97-style global_load_lds staging ----------
// Structure per K-step (T3 minimal 2-phase): issue async STAGE of tile kt+1
// into buf^1 BEFORE ds_read+MFMA of buf; single __syncthreads per step
// (its implicit vmcnt(0)+lgkmcnt(0) drain makes buf^1 ready and buf free).
// LDS layout is LINEAR [row][32] (global_load_lds writes base+lane*16; no pad
// possible). Per m97/m151 this measures 874 vs 646 TF against reg-staging.
template <int BM, int RELU, int RES, int OUTF32, int SPLITZ = 0>
__global__ __launch_bounds__(256) void mfma_gemm(
    const bf16* __restrict__ A, const bf16* __restrict__ Bt,
    const float* __restrict__ bias, const void* __restrict__ resid,
    void* __restrict__ out, float* __restrict__ part,
    int M, int N, int K, int Kstride)
{
    constexpr int MT = BM / 32;  // m-frags per wave (2 or 4)
    __shared__ __align__(16) unsigned short As[2][BM * 32];
    __shared__ __align__(16) unsigned short Bs[2][128 * 32];

    // ---- XCD-aware swizzle of the flattened block id (bijective; nwg%8==0) ----
    int gx = gridDim.x, gy = gridDim.y;
    int lid = (blockIdx.z * gy + blockIdx.y) * gx + blockIdx.x;
    int nwg = gx * gy * gridDim.z;
    int chunk = nwg >> 3;
    int swz = (lid & 7) * chunk + (lid >> 3);
    int bx = swz % gx;
    int by = (swz / gx) % gy;
    int bz = swz / (gx * gy);

    int tid  = threadIdx.x;
    int m0   = by * BM, n0 = bx * 128;
    int lane = tid & 63, wave = tid >> 6;
    int wm = (wave >> 1) * (MT * 16), wn = (wave & 1) * 64;
    int c15 = lane & 15, quad = lane >> 4;

    int koff = 0;
    if constexpr (SPLITZ) koff = bz * K;

    f32x4 acc[MT][4] = {};

    // staging mapping: one gload_lds16 call = 16 rows x 32 cols (64 lanes x 16B)
    int srow = lane >> 2;          // 0..15
    int scol = (lane & 3) * 8;     // 0,8,16,24
    const bf16* abase = A  + (size_t)m0 * Kstride + koff;
    const bf16* bbase = Bt + (size_t)n0 * Kstride + koff;

    auto stage = [&](int buf, int kt) {
        int ko = kt * 32;
        // B: 128 rows -> wave w stages rows w*32 + j*16
#pragma unroll
        for (int j = 0; j < 2; ++j) {
            int r = wave * 32 + j * 16;
            gload_lds16(bbase + (size_t)(r + srow) * Kstride + ko + scol,
                        &Bs[buf][r * 32]);
        }
        if constexpr (BM == 128) {
#pragma unroll
            for (int j = 0; j < 2; ++j) {
                int r = wave * 32 + j * 16;
                gload_lds16(abase + (size_t)(r + srow) * Kstride + ko + scol,
                            &As[buf][r * 32]);
            }
        } else {
            int r = wave * 16;
            gload_lds16(abase + (size_t)(r + srow) * Kstride + ko + scol,
                        &As[buf][r * 32]);
        }
    };

    int nk = K >> 5;
    stage(0, 0);
    __syncthreads();   // tile 0 resident

    for (int kt = 0; kt < nk; ++kt) {
        int buf = kt & 1;
        if (kt + 1 < nk) stage(buf ^ 1, kt + 1);   // async loads in flight across compute

        short8 af[MT], bfr[4];
#pragma unroll
        for (int t = 0; t < MT; ++t)
            af[t]  = *(const short8*)&As[buf][(wm + t * 16 + c15) * 32 + quad * 8];
#pragma unroll
        for (int t = 0; t < 4; ++t)
            bfr[t] = *(const short8*)&Bs[buf][(wn + t * 16 + c15) * 32 + quad * 8];
#pragma unroll
        for (int mt = 0; mt < MT; ++mt)
#pragma unroll
            for (int nt = 0; nt < 4; ++nt)
                acc[mt][nt] = __builtin_amdgcn_mfma_f32_16x16x32_bf16(
                    af[mt], bfr[nt], acc[mt][nt], 0, 0, 0);

        __syncthreads();   // drains vmcnt (buf^1 ready) + lgkmcnt (buf free)
    }

#pragma unroll
    for (int mt = 0; mt < MT; ++mt) {
#pragma unroll
        for (int nt = 0; nt < 4; ++nt) {
            f32x4 v4 = acc[mt][nt];
            int gc = n0 + wn + nt * 16 + c15;
            float bb = (!SPLITZ || bz == 0) ? bias[gc] : 0.0f;
#pragma unroll
            for (int r = 0; r < 4; ++r) {
                int gr = m0 + wm + mt * 16 + quad * 4 + r;
                float v = v4[r] + bb;
                if constexpr (RELU) v = fmaxf(v, 0.0f);
                size_t idx = (size_t)gr * N + gc;
                if constexpr (SPLITZ) {
                    if (bz == 0) {
                        v += b2f(((const bf16*)resid)[idx]);
                        ((float*)out)[idx] = v;
                    } else {
                        part[idx] = v;
                    }
                } else {
                    if constexpr (RES == 1) v += b2f(((const bf16*)resid)[idx]);
                    if constexpr (RES == 2) v += ((const float*)resid)[idx];
                    if constexpr (OUTF32) ((float*)out)[idx] = v;
                    else                  ((bf16*)out)[idx] = f2b(v);
                }
            }
        }
    }
}

// ---------- split-K reduction: out += part (f32, vectorized) ----------
__global__ __launch_bounds__(256) void add_partial(float* __restrict__ out,
                                                   const float* __restrict__ part)
{
    int i = blockIdx.x * 256 + threadIdx.x;
    f32x4 a = ((const f32x4*)out)[i];
    f32x4 p = ((const f32x4*)part)[i];
    a += p;
    ((f32x4*)out)[i] = a;
}

// ---------- MFMA flash attention, transposed orientation + fixed-shift softmax ----------
__global__ __launch_bounds__(256) void flash_attn(const bf16* __restrict__ qkv,
                                                  bf16* __restrict__ ctx)
{
    constexpr int KROW = 72;
    constexpr float CSC = 0.18033688011112042f;  // 0.125 * log2(e)
    constexpr float MSH = 12.0f;                 // fixed exp2-domain shift

    __shared__ __align__(16) unsigned short Qs[128 * KROW];  // aliased by Pt after qf cache
    __shared__ __align__(16) unsigned short Ks[64 * KROW];   // [key][dk]
    __shared__ __align__(16) unsigned short Vt[64 * KROW];   // [dk][key]
    unsigned short* Pt = Qs;                                 // [qrow][key], wave-private rows

    int bx = blockIdx.x;
    int bh = bx & 31;
    int qi = 15 - (bx >> 5);      // heavy q-tiles first
    int h  = bh & 15, b = bh >> 4;
    int q0 = qi * 128;

    int tid = threadIdx.x, lane = tid & 63, w = tid >> 6;
    int c15 = lane & 15, quad = lane >> 4;

    const bf16* base = qkv + (size_t)b * T * QKVN;

    // --- stage Q tile [128][64] ---
    {
        int row = tid >> 1, half = tid & 1;
        const bf16* src = base + (size_t)(q0 + row) * QKVN + h * 64 + half * 32;
        unsigned short* dst = &Qs[row * KROW + half * 32];
        uint4 v0 = *(const uint4*)(src);
        uint4 v1 = *(const uint4*)(src + 8);
        uint4 v2 = *(const uint4*)(src + 16);
        uint4 v3 = *(const uint4*)(src + 24);
        *(uint4*)(dst)      = v0;
        *(uint4*)(dst + 8)  = v1;
        *(uint4*)(dst + 16) = v2;
        *(uint4*)(dst + 24) = v3;
    }
    __syncthreads();

    // Q B-fragments cached in registers (wave-private rows [w*32, w*32+32))
    short8 qf[2][2];
#pragma unroll
    for (int qt = 0; qt < 2; ++qt)
#pragma unroll
        for (int s = 0; s < 2; ++s)
            qf[qt][s] = *(const short8*)&Qs[(w * 32 + qt * 16 + c15) * KROW + s * 32 + quad * 8];

    short8 ones;
#pragma unroll
    for (int i = 0; i < 8; ++i) ones[i] = (short)0x3F80;  // bf16 1.0

    f32x4 Ot[4][2] = {};   // [dt][qt] : O^T[dk][qrow]
    f32x4 lacc[2]  = {};   // row sums per qt

    int nkt   = q0 / 64 + 2;
    int wqmin = q0 + w * 32;
    int wqmax = wqmin + 31;

    for (int kt = 0; kt < nkt; ++kt) {
        int k0 = kt * 64;
        // ---- global loads (K tile + V tile) ----
        int key = tid >> 2, seg = tid & 3;
        const bf16* ksrc = base + (size_t)(k0 + key) * QKVN + D + h * 64 + seg * 16;
        uint4 kv0 = *(const uint4*)ksrc;
        uint4 kv1 = *(const uint4*)(ksrc + 8);
        int keyp = (tid & 31) * 2, dk0 = (tid >> 5) * 8;
        const bf16* vsrc = base + (size_t)(k0 + keyp) * QKVN + 2 * D + h * 64 + dk0;
        uint4 vv0 = *(const uint4*)vsrc;
        uint4 vv1 = *(const uint4*)(vsrc + QKVN);

        __syncthreads();   // previous iteration's Ks/Vt fragment reads complete
        {
            unsigned short* kd = &Ks[key * KROW + seg * 16];
            *(uint4*)kd       = kv0;
            *(uint4*)(kd + 8) = kv1;
            const unsigned short* lo = (const unsigned short*)&vv0;
            const unsigned short* hi = (const unsigned short*)&vv1;
#pragma unroll
            for (int j = 0; j < 8; ++j) {
                unsigned int pk = (unsigned int)lo[j] | ((unsigned int)hi[j] << 16);
                *(unsigned int*)&Vt[(dk0 + j) * KROW + keyp] = pk;  // Vt[dk][key]
            }
        }
        __syncthreads();

        if (k0 <= wqmax) {   // wave-uniform: skip tiles fully above the diagonal
            // ---- S^T = K Q^T : St[ktm][qt], lane holds key=ktm*16+quad*4+r, qrow=qt*16+c15
            f32x4 St[4][2] = {};
#pragma unroll
            for (int s = 0; s < 2; ++s)
#pragma unroll
                for (int ktm = 0; ktm < 4; ++ktm) {
                    short8 kf = *(const short8*)&Ks[(ktm * 16 + c15) * KROW + s * 32 + quad * 8];
#pragma unroll
                    for (int qt = 0; qt < 2; ++qt)
                        St[ktm][qt] = __builtin_amdgcn_mfma_f32_16x16x32_bf16(
                            kf, qf[qt][s], St[ktm][qt], 0, 0, 0);
                }

            // ---- P = exp2(S*CSC - MSH) (+ causal mask on diagonal tiles), store to Pt ----
            bool diag = (k0 + 63 > wqmin);
#pragma unroll
            for (int ktm = 0; ktm < 4; ++ktm)
#pragma unroll
                for (int qt = 0; qt < 2; ++qt) {
                    ushort4 pk;
                    int q_g = wqmin + qt * 16 + c15;
#pragma unroll
                    for (int r = 0; r < 4; ++r) {
                        float p = fast_exp2(fmaf(St[ktm][qt][r], CSC, -MSH));
                        if (diag && (k0 + ktm * 16 + quad * 4 + r > q_g)) p = 0.0f;
                        ((unsigned short*)&pk)[r] = f2bu(p);
                    }
                    *(ushort4*)&Pt[(w * 32 + qt * 16 + c15) * KROW + ktm * 16 + quad * 4] = pk;
                }

            // ---- O^T += V^T P^T ; l += ones . P^T  (wave-private, no barrier) ----
#pragma unroll
            for (int s = 0; s < 2; ++s) {
                short8 pf[2];
#pragma unroll
                for (int qt = 0; qt < 2; ++qt)
                    pf[qt] = *(const short8*)&Pt[(w * 32 + qt * 16 + c15) * KROW + s * 32 + quad * 8];
#pragma unroll
                for (int qt = 0; qt < 2; ++qt)
                    lacc[qt] = __builtin_amdgcn_mfma_f32_16x16x32_bf16(ones, pf[qt], lacc[qt], 0, 0, 0);
#pragma unroll
                for (int dt = 0; dt < 4; ++dt) {
                    short8 vf = *(const short8*)&Vt[(dt * 16 + c15) * KROW + s * 32 + quad * 8];
#pragma unroll
                    for (int qt = 0; qt < 2; ++qt)
                        Ot[dt][qt] = __builtin_amdgcn_mfma_f32_16x16x32_bf16(
                            vf, pf[qt], Ot[dt][qt], 0, 0, 0);
                }
            }
        }
    }

    // ---- epilogue: ctx[qrow][h*64+dk] = O^T / l, packed 8 B stores ----
#pragma unroll
    for (int qt = 0; qt < 2; ++qt) {
        float inv = 1.0f / lacc[qt][0];
        int grow = b * T + q0 + w * 32 + qt * 16 + c15;
        bf16* dst = ctx + (size_t)grow * D + h * 64 + quad * 4;
#pragma unroll
        for (int dt = 0; dt < 4; ++dt) {
            ushort4 pk;
#pragma unroll
            for (int r = 0; r < 4; ++r)
                ((unsigned short*)&pk)[r] = f2bu(Ot[dt][qt][r] * inv);
            *(ushort4*)(dst + dt * 16) = pk;
        }
    }
}

extern "C" void kernel_launch(void* const* d_in, const int* in_sizes, int n_in,
                              void* d_out, int out_size, void* d_ws, size_t ws_size,
                              hipStream_t stream)
{
    const float* X    = (const float*)d_in[0];
    const float* Wqkv = (const float*)d_in[1];
    const float* bqkv = (const float*)d_in[2];
    const float* Wo   = (const float*)d_in[3];
    const float* bo   = (const float*)d_in[4];
    const float* W1   = (const float*)d_in[5];
    const float* b1   = (const float*)d_in[6];
    const float* W2   = (const float*)d_in[7];
    const float* b2   = (const float*)d_in[8];
    const float* ln1g = (const float*)d_in[9];
    const float* ln1b = (const float*)d_in[10];
    const float* ln2g = (const float*)d_in[11];
    const float* ln2b = (const float*)d_in[12];
    float* out = (float*)d_out;

    // Workspace (peak 72 MiB):
    char* ws = (char*)d_ws;
    bf16* Wqkv_t = (bf16*)(ws + 0);          // [3072][1024]  6 MiB
    bf16* Wo_t   = (bf16*)(ws + 6291456);    // [1024][1024]  2 MiB
    bf16* W1_t   = (bf16*)(ws + 8388608);    // [4096][1024]  8 MiB
    bf16* W2_t   = (bf16*)(ws + 16777216);   // [1024][4096]  8 MiB
    bf16* Xn     = (bf16*)(ws + 25165824);   // 8 MiB; reused by X1 after step 2
    bf16* X1     = Xn;
    bf16* qkv    = (bf16*)(ws + 33554432);   // 24 MiB; first 8 MiB reused by Xn2 after attn
    bf16* Xn2    = (bf16*)(ws + 33554432);
    bf16* ctx    = (bf16*)(ws + 58720256);   // 8 MiB
    bf16* mid    = (bf16*)(ws + 41943040);   // 32 MiB; ends at 72 MiB
    // Split-K partial for W2: reuses ws[0..16 MiB) (Wqkv_t/Wo_t/W1_t are dead
    // by the time the W2 GEMM runs).
    float* W2part = (float*)(ws + 0);        // [4096][1024] f32, exactly 16 MiB

    transpose_cast<<<dim3(QKVN / 32, D / 32), 256, 0, stream>>>(Wqkv, Wqkv_t, D, QKVN);
    transpose_cast<<<dim3(D / 32, D / 32), 256, 0, stream>>>(Wo, Wo_t, D, D);
    transpose_cast<<<dim3(FFNN / 32, D / 32), 256, 0, stream>>>(W1, W1_t, D, FFNN);
    transpose_cast<<<dim3(D / 32, FFNN / 32), 256, 0, stream>>>(W2, W2_t, FFNN, D);

    ln_kernel<float><<<ROWS, 256, 0, stream>>>(X, ln1g, ln1b, Xn);
    mfma_gemm<128, 0, 0, 0><<<dim3(QKVN / 128, ROWS / 128), 256, 0, stream>>>(
        Xn, Wqkv_t, bqkv, nullptr, qkv, nullptr, ROWS, QKVN, D, D);
    flash_attn<<<512, 256, 0, stream>>>(qkv, ctx);
    mfma_gemm<64, 0, 2, 0><<<dim3(D / 128, ROWS / 64), 256, 0, stream>>>(
        ctx, Wo_t, bo, X, X1, nullptr, ROWS, D, D, D);
    ln_kernel<bf16><<<ROWS, 256, 0, stream>>>(X1, ln2g, ln2b, Xn2);
    mfma_gemm<128, 1, 0, 0><<<dim3(FFNN / 128, ROWS / 128), 256, 0, stream>>>(
        Xn2, W1_t, b1, nullptr, mid, nullptr, ROWS, FFNN, D, D);
    // W2: split-K=2 in one dispatch (z=0: K[0,2048) -> out with bias+resid;
    // z=1: K[2048,4096) -> raw f32 partial), then out += partial.
    mfma_gemm<64, 0, 1, 1, 1><<<dim3(D / 128, ROWS / 64, 2), 256, 0, stream>>>(
        mid, W2_t, b2, X1, out, W2part, ROWS, D, FFNN / 2, FFNN);
    add_partial<<<ROWS * D / 4 / 256, 256, 0, stream>>>(out, W2part);
}

// Round 3
// 347.044 us; speedup vs baseline: 1.0798x; 1.0451x over previous
//
#include <hip/hip_runtime.h>
#include <hip/hip_bf16.h>

typedef __hip_bfloat16 bf16;
typedef __attribute__((ext_vector_type(8))) short short8;   // 8 bf16 (4 VGPRs)
typedef __attribute__((ext_vector_type(4))) float f32x4;

constexpr int D     = 1024;
constexpr int T     = 2048;
constexpr int BATCH = 2;
constexpr int ROWS  = BATCH * T;   // 4096
constexpr int NH    = 16;
constexpr int DKEY  = 64;
constexpr int QKVN  = 3 * D;       // 3072
constexpr int FFNN  = 4 * D;       // 4096

static __device__ __forceinline__ float b2f(bf16 x) { return __bfloat162float(x); }
static __device__ __forceinline__ bf16  f2b(float x) { return __float2bfloat16(x); }
static __device__ __forceinline__ float loadf(const bf16* p)  { return __bfloat162float(*p); }
static __device__ __forceinline__ float loadf(const float* p) { return *p; }
static __device__ __forceinline__ float fast_exp2(float x) { return __builtin_amdgcn_exp2f(x); }
static __device__ __forceinline__ unsigned short f2bu(float x) {
    return __bfloat16_as_ushort(__float2bfloat16(x));
}

// async global->LDS, 16 B per lane. LDS dest is wave-uniform base + lane*16.
static __device__ __forceinline__ void gload_lds16(const bf16* g, unsigned short* l) {
    __builtin_amdgcn_global_load_lds(
        (const __attribute__((address_space(1))) void*)g,
        (__attribute__((address_space(3))) void*)l,
        16, 0, 0);
}

// ---------- fp32 [R][C] -> bf16 [C][R] transpose + downcast ----------
__global__ __launch_bounds__(256) void transpose_cast(const float* __restrict__ in,
                                                      bf16* __restrict__ out,
                                                      int R, int C)
{
    __shared__ float tile[32][33];
    int c0 = blockIdx.x * 32, r0 = blockIdx.y * 32;
    int tx = threadIdx.x & 31, ty = threadIdx.x >> 5;  // 8 rows per pass
#pragma unroll
    for (int i = 0; i < 32; i += 8)
        tile[ty + i][tx] = in[(size_t)(r0 + ty + i) * C + c0 + tx];
    __syncthreads();
#pragma unroll
    for (int i = 0; i < 32; i += 8)
        out[(size_t)(c0 + ty + i) * R + r0 + tx] = f2b(tile[tx][ty + i]);
}

// ---------- LayerNorm: one block per row of 1024, fp32 gamma/beta, bf16 out ----------
template <typename TIN>
__global__ __launch_bounds__(256) void ln_kernel(const TIN* __restrict__ X,
                                                 const float* __restrict__ g,
                                                 const float* __restrict__ b,
                                                 bf16* __restrict__ out)
{
    int row = blockIdx.x;
    int tid = threadIdx.x;
    const TIN* xr = X + (size_t)row * D;
    float v[4];
#pragma unroll
    for (int i = 0; i < 4; ++i) v[i] = loadf(xr + tid + i * 256);

    float s1 = v[0] + v[1] + v[2] + v[3];
    float s2 = v[0]*v[0] + v[1]*v[1] + v[2]*v[2] + v[3]*v[3];
#pragma unroll
    for (int off = 32; off; off >>= 1) {
        s1 += __shfl_xor(s1, off);
        s2 += __shfl_xor(s2, off);
    }
    __shared__ float red[8];
    int lane = tid & 63, w = tid >> 6;
    if (lane == 0) { red[w] = s1; red[4 + w] = s2; }
    __syncthreads();
    s1 = red[0] + red[1] + red[2] + red[3];
    s2 = red[4] + red[5] + red[6] + red[7];

    float mu   = s1 * (1.0f / D);
    float var  = s2 * (1.0f / D) - mu * mu;
    float rstd = rsqrtf(var + 1e-5f);

    bf16* orow = out + (size_t)row * D;
#pragma unroll
    for (int i = 0; i < 4; ++i) {
        int c = tid + i * 256;
        orow[c] = f2b((v[i] - mu) * rstd * g[c] + b[c]);
    }
}

// ---------- MFMA GEMM, m97-style global_load_lds staging ----------
template <int BM, int RELU, int RES, int OUTF32, int SPLITZ = 0>
__global__ __launch_bounds__(256) void mfma_gemm(
    const bf16* __restrict__ A, const bf16* __restrict__ Bt,
    const float* __restrict__ bias, const void* __restrict__ resid,
    void* __restrict__ out, float* __restrict__ part,
    int M, int N, int K, int Kstride)
{
    constexpr int MT = BM / 32;  // m-frags per wave (2 or 4)
    __shared__ __align__(16) unsigned short As[2][BM * 32];
    __shared__ __align__(16) unsigned short Bs[2][128 * 32];

    // ---- XCD-aware swizzle of the flattened block id (bijective; nwg%8==0) ----
    int gx = gridDim.x, gy = gridDim.y;
    int lid = (blockIdx.z * gy + blockIdx.y) * gx + blockIdx.x;
    int nwg = gx * gy * gridDim.z;
    int chunk = nwg >> 3;
    int swz = (lid & 7) * chunk + (lid >> 3);
    int bx = swz % gx;
    int by = (swz / gx) % gy;
    int bz = swz / (gx * gy);

    int tid  = threadIdx.x;
    int m0   = by * BM, n0 = bx * 128;
    int lane = tid & 63, wave = tid >> 6;
    int wm = (wave >> 1) * (MT * 16), wn = (wave & 1) * 64;
    int c15 = lane & 15, quad = lane >> 4;

    int koff = 0;
    if constexpr (SPLITZ) koff = bz * K;

    f32x4 acc[MT][4] = {};

    // staging mapping: one gload_lds16 call = 16 rows x 32 cols (64 lanes x 16B)
    int srow = lane >> 2;          // 0..15
    int scol = (lane & 3) * 8;     // 0,8,16,24
    const bf16* abase = A  + (size_t)m0 * Kstride + koff;
    const bf16* bbase = Bt + (size_t)n0 * Kstride + koff;

    auto stage = [&](int buf, int kt) {
        int ko = kt * 32;
#pragma unroll
        for (int j = 0; j < 2; ++j) {
            int r = wave * 32 + j * 16;
            gload_lds16(bbase + (size_t)(r + srow) * Kstride + ko + scol,
                        &Bs[buf][r * 32]);
        }
        if constexpr (BM == 128) {
#pragma unroll
            for (int j = 0; j < 2; ++j) {
                int r = wave * 32 + j * 16;
                gload_lds16(abase + (size_t)(r + srow) * Kstride + ko + scol,
                            &As[buf][r * 32]);
            }
        } else {
            int r = wave * 16;
            gload_lds16(abase + (size_t)(r + srow) * Kstride + ko + scol,
                        &As[buf][r * 32]);
        }
    };

    int nk = K >> 5;
    stage(0, 0);
    __syncthreads();   // tile 0 resident

    for (int kt = 0; kt < nk; ++kt) {
        int buf = kt & 1;
        if (kt + 1 < nk) stage(buf ^ 1, kt + 1);   // async loads in flight across compute

        short8 af[MT], bfr[4];
#pragma unroll
        for (int t = 0; t < MT; ++t)
            af[t]  = *(const short8*)&As[buf][(wm + t * 16 + c15) * 32 + quad * 8];
#pragma unroll
        for (int t = 0; t < 4; ++t)
            bfr[t] = *(const short8*)&Bs[buf][(wn + t * 16 + c15) * 32 + quad * 8];
#pragma unroll
        for (int mt = 0; mt < MT; ++mt)
#pragma unroll
            for (int nt = 0; nt < 4; ++nt)
                acc[mt][nt] = __builtin_amdgcn_mfma_f32_16x16x32_bf16(
                    af[mt], bfr[nt], acc[mt][nt], 0, 0, 0);

        __syncthreads();   // drains vmcnt (buf^1 ready) + lgkmcnt (buf free)
    }

#pragma unroll
    for (int mt = 0; mt < MT; ++mt) {
#pragma unroll
        for (int nt = 0; nt < 4; ++nt) {
            f32x4 v4 = acc[mt][nt];
            int gc = n0 + wn + nt * 16 + c15;
            float bb = (!SPLITZ || bz == 0) ? bias[gc] : 0.0f;
#pragma unroll
            for (int r = 0; r < 4; ++r) {
                int gr = m0 + wm + mt * 16 + quad * 4 + r;
                float v = v4[r] + bb;
                if constexpr (RELU) v = fmaxf(v, 0.0f);
                size_t idx = (size_t)gr * N + gc;
                if constexpr (SPLITZ) {
                    if (bz == 0) {
                        v += b2f(((const bf16*)resid)[idx]);
                        ((float*)out)[idx] = v;
                    } else {
                        part[idx] = v;
                    }
                } else {
                    if constexpr (RES == 1) v += b2f(((const bf16*)resid)[idx]);
                    if constexpr (RES == 2) v += ((const float*)resid)[idx];
                    if constexpr (OUTF32) ((float*)out)[idx] = v;
                    else                  ((bf16*)out)[idx] = f2b(v);
                }
            }
        }
    }
}

// ---------- split-K reduction: out += part (f32, vectorized) ----------
__global__ __launch_bounds__(256) void add_partial(float* __restrict__ out,
                                                   const float* __restrict__ part)
{
    int i = blockIdx.x * 256 + threadIdx.x;
    f32x4 a = ((const f32x4*)out)[i];
    f32x4 p = ((const f32x4*)part)[i];
    a += p;
    ((f32x4*)out)[i] = a;
}

// ---------- MFMA flash attention ----------
// Round 3: QBLK 128 -> 64 (grid 512 -> 1024 blocks) to fix 11.7% occupancy.
// Each of 4 waves owns 16 q-rows. Causal mask branch hoisted: only the single
// diagonal k-tile (kt == nkt-1) runs the compare/cndmask path.
__global__ __launch_bounds__(256) void flash_attn(const bf16* __restrict__ qkv,
                                                  bf16* __restrict__ ctx)
{
    constexpr int KROW = 72;
    constexpr float CSC = 0.18033688011112042f;  // 0.125 * log2(e)
    constexpr float MSH = 12.0f;                 // fixed exp2-domain shift

    __shared__ __align__(16) unsigned short Qs[64 * KROW];   // aliased by Pt after qf cache
    __shared__ __align__(16) unsigned short Ks[64 * KROW];   // [key][dk]
    __shared__ __align__(16) unsigned short Vt[64 * KROW];   // [dk][key]
    unsigned short* Pt = Qs;                                 // [qrow][key], wave-private rows

    int bx = blockIdx.x;
    int bh = bx & 31;
    int qi = 31 - (bx >> 5);      // heavy q-tiles first
    int h  = bh & 15, b = bh >> 4;
    int q0 = qi * 64;

    int tid = threadIdx.x, lane = tid & 63, w = tid >> 6;
    int c15 = lane & 15, quad = lane >> 4;

    const bf16* base = qkv + (size_t)b * T * QKVN;

    // --- stage Q tile [64][64] : 256 threads x 16 elems ---
    {
        int row = tid >> 2, qtr = tid & 3;
        const bf16* src = base + (size_t)(q0 + row) * QKVN + h * 64 + qtr * 16;
        unsigned short* dst = &Qs[row * KROW + qtr * 16];
        uint4 v0 = *(const uint4*)(src);
        uint4 v1 = *(const uint4*)(src + 8);
        *(uint4*)(dst)     = v0;
        *(uint4*)(dst + 8) = v1;
    }
    __syncthreads();

    // Q B-fragments cached in registers (wave-private rows [w*16, w*16+16))
    short8 qf[2];
#pragma unroll
    for (int s = 0; s < 2; ++s)
        qf[s] = *(const short8*)&Qs[(w * 16 + c15) * KROW + s * 32 + quad * 8];

    short8 ones;
#pragma unroll
    for (int i = 0; i < 8; ++i) ones[i] = (short)0x3F80;  // bf16 1.0

    f32x4 Ot[4] = {};   // [dt] : O^T[dk][qrow]
    f32x4 lacc  = {};   // row sums

    int nkt   = q0 / 64 + 1;
    int wqmin = q0 + w * 16;

    for (int kt = 0; kt < nkt; ++kt) {
        int k0 = kt * 64;
        // ---- global loads (K tile + V tile) ----
        int key = tid >> 2, seg = tid & 3;
        const bf16* ksrc = base + (size_t)(k0 + key) * QKVN + D + h * 64 + seg * 16;
        uint4 kv0 = *(const uint4*)ksrc;
        uint4 kv1 = *(const uint4*)(ksrc + 8);
        int keyp = (tid & 31) * 2, dk0 = (tid >> 5) * 8;
        const bf16* vsrc = base + (size_t)(k0 + keyp) * QKVN + 2 * D + h * 64 + dk0;
        uint4 vv0 = *(const uint4*)vsrc;
        uint4 vv1 = *(const uint4*)(vsrc + QKVN);

        __syncthreads();   // previous iteration's Ks/Vt fragment reads complete
        {
            unsigned short* kd = &Ks[key * KROW + seg * 16];
            *(uint4*)kd       = kv0;
            *(uint4*)(kd + 8) = kv1;
            const unsigned short* lo = (const unsigned short*)&vv0;
            const unsigned short* hi = (const unsigned short*)&vv1;
#pragma unroll
            for (int j = 0; j < 8; ++j) {
                unsigned int pk = (unsigned int)lo[j] | ((unsigned int)hi[j] << 16);
                *(unsigned int*)&Vt[(dk0 + j) * KROW + keyp] = pk;  // Vt[dk][key]
            }
        }
        __syncthreads();

        // ---- S^T = K Q^T : St[ktm], lane holds key=ktm*16+quad*4+r, qrow=c15
        f32x4 St[4] = {};
#pragma unroll
        for (int s = 0; s < 2; ++s)
#pragma unroll
            for (int ktm = 0; ktm < 4; ++ktm) {
                short8 kf = *(const short8*)&Ks[(ktm * 16 + c15) * KROW + s * 32 + quad * 8];
                St[ktm] = __builtin_amdgcn_mfma_f32_16x16x32_bf16(kf, qf[s], St[ktm], 0, 0, 0);
            }

        // ---- P = exp2(S*CSC - MSH); causal mask only on the diagonal tile ----
        if (kt == nkt - 1) {
            int q_g = wqmin + c15;
#pragma unroll
            for (int ktm = 0; ktm < 4; ++ktm) {
                ushort4 pk;
#pragma unroll
                for (int r = 0; r < 4; ++r) {
                    float p = fast_exp2(fmaf(St[ktm][r], CSC, -MSH));
                    if (k0 + ktm * 16 + quad * 4 + r > q_g) p = 0.0f;
                    ((unsigned short*)&pk)[r] = f2bu(p);
                }
                *(ushort4*)&Pt[(w * 16 + c15) * KROW + ktm * 16 + quad * 4] = pk;
            }
        } else {
#pragma unroll
            for (int ktm = 0; ktm < 4; ++ktm) {
                ushort4 pk;
#pragma unroll
                for (int r = 0; r < 4; ++r)
                    ((unsigned short*)&pk)[r] = f2bu(fast_exp2(fmaf(St[ktm][r], CSC, -MSH)));
                *(ushort4*)&Pt[(w * 16 + c15) * KROW + ktm * 16 + quad * 4] = pk;
            }
        }

        // ---- O^T += V^T P^T ; l += ones . P^T  (wave-private, no barrier) ----
#pragma unroll
        for (int s = 0; s < 2; ++s) {
            short8 pf = *(const short8*)&Pt[(w * 16 + c15) * KROW + s * 32 + quad * 8];
            lacc = __builtin_amdgcn_mfma_f32_16x16x32_bf16(ones, pf, lacc, 0, 0, 0);
#pragma unroll
            for (int dt = 0; dt < 4; ++dt) {
                short8 vf = *(const short8*)&Vt[(dt * 16 + c15) * KROW + s * 32 + quad * 8];
                Ot[dt] = __builtin_amdgcn_mfma_f32_16x16x32_bf16(vf, pf, Ot[dt], 0, 0, 0);
            }
        }
    }

    // ---- epilogue: ctx[qrow][h*64+dk] = O^T / l, packed 8 B stores ----
    {
        float inv = 1.0f / lacc[0];
        int grow = b * T + q0 + w * 16 + c15;
        bf16* dst = ctx + (size_t)grow * D + h * 64 + quad * 4;
#pragma unroll
        for (int dt = 0; dt < 4; ++dt) {
            ushort4 pk;
#pragma unroll
            for (int r = 0; r < 4; ++r)
                ((unsigned short*)&pk)[r] = f2bu(Ot[dt][r] * inv);
            *(ushort4*)(dst + dt * 16) = pk;
        }
    }
}

extern "C" void kernel_launch(void* const* d_in, const int* in_sizes, int n_in,
                              void* d_out, int out_size, void* d_ws, size_t ws_size,
                              hipStream_t stream)
{
    const float* X    = (const float*)d_in[0];
    const float* Wqkv = (const float*)d_in[1];
    const float* bqkv = (const float*)d_in[2];
    const float* Wo   = (const float*)d_in[3];
    const float* bo   = (const float*)d_in[4];
    const float* W1   = (const float*)d_in[5];
    const float* b1   = (const float*)d_in[6];
    const float* W2   = (const float*)d_in[7];
    const float* b2   = (const float*)d_in[8];
    const float* ln1g = (const float*)d_in[9];
    const float* ln1b = (const float*)d_in[10];
    const float* ln2g = (const float*)d_in[11];
    const float* ln2b = (const float*)d_in[12];
    float* out = (float*)d_out;

    // Workspace (peak 72 MiB):
    char* ws = (char*)d_ws;
    bf16* Wqkv_t = (bf16*)(ws + 0);          // [3072][1024]  6 MiB
    bf16* Wo_t   = (bf16*)(ws + 6291456);    // [1024][1024]  2 MiB
    bf16* W1_t   = (bf16*)(ws + 8388608);    // [4096][1024]  8 MiB
    bf16* W2_t   = (bf16*)(ws + 16777216);   // [1024][4096]  8 MiB
    bf16* Xn     = (bf16*)(ws + 25165824);   // 8 MiB; reused by X1 after step 2
    bf16* X1     = Xn;
    bf16* qkv    = (bf16*)(ws + 33554432);   // 24 MiB; first 8 MiB reused by Xn2 after attn
    bf16* Xn2    = (bf16*)(ws + 33554432);
    bf16* ctx    = (bf16*)(ws + 58720256);   // 8 MiB
    bf16* mid    = (bf16*)(ws + 41943040);   // 32 MiB; ends at 72 MiB
    float* W2part = (float*)(ws + 0);        // [4096][1024] f32, exactly 16 MiB

    transpose_cast<<<dim3(QKVN / 32, D / 32), 256, 0, stream>>>(Wqkv, Wqkv_t, D, QKVN);
    transpose_cast<<<dim3(D / 32, D / 32), 256, 0, stream>>>(Wo, Wo_t, D, D);
    transpose_cast<<<dim3(FFNN / 32, D / 32), 256, 0, stream>>>(W1, W1_t, D, FFNN);
    transpose_cast<<<dim3(D / 32, FFNN / 32), 256, 0, stream>>>(W2, W2_t, FFNN, D);

    ln_kernel<float><<<ROWS, 256, 0, stream>>>(X, ln1g, ln1b, Xn);
    mfma_gemm<128, 0, 0, 0><<<dim3(QKVN / 128, ROWS / 128), 256, 0, stream>>>(
        Xn, Wqkv_t, bqkv, nullptr, qkv, nullptr, ROWS, QKVN, D, D);
    flash_attn<<<1024, 256, 0, stream>>>(qkv, ctx);
    mfma_gemm<64, 0, 2, 0><<<dim3(D / 128, ROWS / 64), 256, 0, stream>>>(
        ctx, Wo_t, bo, X, X1, nullptr, ROWS, D, D, D);
    ln_kernel<bf16><<<ROWS, 256, 0, stream>>>(X1, ln2g, ln2b, Xn2);
    mfma_gemm<128, 1, 0, 0><<<dim3(FFNN / 128, ROWS / 128), 256, 0, stream>>>(
        Xn2, W1_t, b1, nullptr, mid, nullptr, ROWS, FFNN, D, D);
    mfma_gemm<64, 0, 1, 1, 1><<<dim3(D / 128, ROWS / 64, 2), 256, 0, stream>>>(
        mid, W2_t, b2, X1, out, W2part, ROWS, D, FFNN / 2, FFNN);
    add_partial<<<ROWS * D / 4 / 256, 256, 0, stream>>>(out, W2part);
}